// Round 10
// baseline (369.873 us; speedup 1.0000x reference)
//
#include <hip/hip_runtime.h>
#include <hip/hip_bf16.h>
#include <cstdint>

// Problem constants
#define BB  8
#define CH  64
#define TT  4096
#define KNN 9
#define NEG_INF (-3.402823466e38f)
#define SLOTS 80          // candidate bucket per row (4 col-quarters feed it)
#define KTH   12          // θ = 12th largest of per-quarter lane-union

typedef short  s16x8 __attribute__((ext_vector_type(8)));   // 8 bf16 MFMA frag
typedef float  f32x4 __attribute__((ext_vector_type(4)));   // MFMA acc

// Workspace layout (float units) — end 16,060,416 floats = 64.2 MB
constexpr size_t OFF_UB  = 0;                                  // u bf16 [B][9][T][C] ushort
constexpr size_t OFF_QTF = (size_t)BB*KNN*TT*CH/2;             //  9,437,184 qhatT f32 [B][T][C]
constexpr size_t OFF_KTF = OFF_QTF + (size_t)BB*TT*CH;         // 11,534,336 khatT f32
constexpr size_t OFF_QTB = OFF_KTF + (size_t)BB*TT*CH;         // 13,631,488 qhatT bf16 ushort
constexpr size_t OFF_KTB = OFF_QTB + (size_t)BB*TT*CH/2;       // 14,680,064 khatT bf16
constexpr size_t OFF_IDX = OFF_KTB + (size_t)BB*TT*CH/2;       // 15,728,640 idx [B][T][9]
constexpr size_t OFF_CWP = OFF_IDX + (size_t)BB*TT*KNN;        // 16,023,552 cwp [9][64][64]

__device__ __forceinline__ unsigned short f2bf(float f) {
    unsigned u = __float_as_uint(f);
    return (unsigned short)((u + 0x7FFFu + ((u >> 16) & 1u)) >> 16);
}

// value-only ascending top-4 (3 med3 + 1 max); reference params keep SROA.
__device__ __forceinline__ void insert4(float w, float (&s)[4]) {
    s[0] = __builtin_amdgcn_fmed3f(s[0], s[1], w);
    s[1] = __builtin_amdgcn_fmed3f(s[1], s[2], w);
    s[2] = __builtin_amdgcn_fmed3f(s[2], s[3], w);
    s[3] = fmaxf(s[3], w);
}

// θ = KTH-th largest of the union of a quad's 16 top-4 lists (destroys lists).
// Union ⊆ quarter-row ⇒ θ ≤ quarter's KTH-th largest (safe threshold).
__device__ __forceinline__ float popTheta4(float (&s)[4], int lane) {
    float theta = NEG_INF;
    #pragma unroll 1
    for (int p = 0; p < KTH; ++p) {
        float h = s[3];
        float m = h;
        m = fmaxf(m, __shfl_xor(m, 1));
        m = fmaxf(m, __shfl_xor(m, 2));
        m = fmaxf(m, __shfl_xor(m, 4));
        m = fmaxf(m, __shfl_xor(m, 8));
        unsigned long long bal = __ballot(h == m);
        unsigned qb = (unsigned)((bal >> (lane & 48)) & 0xFFFFull);
        int owner = __ffs(qb) - 1;
        if ((lane & 15) == owner) {
            s[3] = s[2]; s[2] = s[1]; s[1] = s[0]; s[0] = NEG_INF;
        }
        theta = m;
    }
    return theta;
}

// exact sorted-9 insert, value desc w/ index-asc tiebreak (final sort only)
__device__ __forceinline__ void insert9x(float w, int wi, float (&s)[9], int (&si)[9]) {
    bool c[9];
    #pragma unroll
    for (int k = 0; k < 9; ++k) c[k] = (w > s[k]) || (w == s[k] && wi < si[k]);
    #pragma unroll
    for (int k = 0; k < 8; ++k) si[k] = c[k + 1] ? si[k + 1] : (c[k] ? wi : si[k]);
    si[8] = c[8] ? wi : si[8];
    #pragma unroll
    for (int k = 0; k < 8; ++k) s[k] = c[k + 1] ? s[k + 1] : (c[k] ? w : s[k]);
    s[8] = c[8] ? w : s[8];
}

// ---------------------------------------------------------------------------
// K0: repack conv_w[o][cc*9+kk] -> cwp[kk][cc][o]
// ---------------------------------------------------------------------------
__global__ void repack_cw_kernel(const float* __restrict__ cw, float* __restrict__ cwp) {
    int e = blockIdx.x * blockDim.x + threadIdx.x;
    if (e >= KNN * CH * CH) return;
    int o  = e & 63;
    int cc = (e >> 6) & 63;
    int kk = e >> 12;
    cwp[e] = cw[o * (CH * KNN) + cc * KNN + kk];
}

// ---------------------------------------------------------------------------
// K1: QKV + L2 normalize + u-projection (u bf16) + q/k T-layout fp32 & bf16
// ---------------------------------------------------------------------------
__global__ __launch_bounds__(256) void qkvu_kernel(
        const float* __restrict__ x,
        const float* __restrict__ Wq, const float* __restrict__ Wk, const float* __restrict__ Wv,
        const float* __restrict__ cwp,
        float* __restrict__ qtf, float* __restrict__ ktf,
        unsigned short* __restrict__ qtb, unsigned short* __restrict__ ktb,
        unsigned short* __restrict__ ub) {
    __shared__ __align__(16) float xs[CH * 64];
    __shared__ __align__(16) float vs[CH * 64];
    __shared__ __align__(16) float wl[CH * 64];
    __shared__ float pq[4 * 64], pk[4 * 64];

    const int b   = blockIdx.x >> 6;
    const int tb  = blockIdx.x & 63;
    const int tid = threadIdx.x;

    const float* xb = x + ((size_t)b * CH) * TT + tb * 64;
    #pragma unroll
    for (int m = 0; m < 16; ++m) {
        int l = tid + 256 * m;
        xs[l] = xb[(size_t)(l >> 6) * TT + (l & 63)];
    }
    __syncthreads();

    const int t = tid & 63;
    const int g = __builtin_amdgcn_readfirstlane(tid >> 6);
    const int d0 = g * 16;

    float qa[16], ka[16], va[16];
    #pragma unroll
    for (int dd = 0; dd < 16; ++dd) { qa[dd] = 0.f; ka[dd] = 0.f; va[dd] = 0.f; }

    #pragma unroll 4
    for (int c = 0; c < CH; ++c) {
        float xv = xs[c * 64 + t];
        #pragma unroll
        for (int dd = 0; dd < 16; ++dd) {
            qa[dd] = fmaf(Wq[(d0 + dd) * CH + c], xv, qa[dd]);
            ka[dd] = fmaf(Wk[(d0 + dd) * CH + c], xv, ka[dd]);
            va[dd] = fmaf(Wv[(d0 + dd) * CH + c], xv, va[dd]);
        }
    }

    float sq = 0.f, sk = 0.f;
    #pragma unroll
    for (int dd = 0; dd < 16; ++dd) { sq = fmaf(qa[dd], qa[dd], sq); sk = fmaf(ka[dd], ka[dd], sk); }
    pq[g * 64 + t] = sq;
    pk[g * 64 + t] = sk;
    __syncthreads();

    const float nq = sqrtf(pq[t] + pq[64 + t] + pq[128 + t] + pq[192 + t]);
    const float nk = sqrtf(pk[t] + pk[64 + t] + pk[128 + t] + pk[192 + t]);
    const float isq = 1.0f / fmaxf(nq, 1e-12f);
    const float isk = 1.0f / fmaxf(nk, 1e-12f);

    const size_t tg = (size_t)tb * 64 + t;
    float qn[16], kn[16];
    #pragma unroll
    for (int dd = 0; dd < 16; ++dd) {
        qn[dd] = qa[dd] * isq;
        kn[dd] = ka[dd] * isk;
        vs[(d0 + dd) * 64 + t] = va[dd];
    }
    float* qf = qtf + ((size_t)b * TT + tg) * CH + d0;
    float* kf = ktf + ((size_t)b * TT + tg) * CH + d0;
    #pragma unroll
    for (int p = 0; p < 4; ++p) {
        *(float4*)&qf[p * 4] = make_float4(qn[p*4], qn[p*4+1], qn[p*4+2], qn[p*4+3]);
        *(float4*)&kf[p * 4] = make_float4(kn[p*4], kn[p*4+1], kn[p*4+2], kn[p*4+3]);
    }
    unsigned* qh = (unsigned*)(qtb + ((size_t)b * TT + tg) * CH + d0);
    unsigned* kh = (unsigned*)(ktb + ((size_t)b * TT + tg) * CH + d0);
    #pragma unroll
    for (int p = 0; p < 8; ++p) {
        qh[p] = (unsigned)f2bf(qn[2*p]) | ((unsigned)f2bf(qn[2*p+1]) << 16);
        kh[p] = (unsigned)f2bf(kn[2*p]) | ((unsigned)f2bf(kn[2*p+1]) << 16);
    }
    __syncthreads();

    const int to = tid & 15;
    const int tt = tid >> 4;
    for (int kk = 0; kk < KNN; ++kk) {
        #pragma unroll
        for (int m = 0; m < 16; ++m) {
            int l = tid + 256 * m;
            wl[l] = cwp[kk * (CH * CH) + l];
        }
        __syncthreads();
        float acc[4][4];
        #pragma unroll
        for (int i = 0; i < 4; ++i)
            #pragma unroll
            for (int j = 0; j < 4; ++j) acc[i][j] = 0.f;

        #pragma unroll 8
        for (int cc = 0; cc < CH; ++cc) {
            float4 wv = *(const float4*)&wl[cc * 64 + 4 * to];
            float4 vv = *(const float4*)&vs[cc * 64 + 4 * tt];
            const float wj[4] = {wv.x, wv.y, wv.z, wv.w};
            const float vi[4] = {vv.x, vv.y, vv.z, vv.w};
            #pragma unroll
            for (int i = 0; i < 4; ++i)
                #pragma unroll
                for (int j = 0; j < 4; ++j) acc[i][j] = fmaf(vi[i], wj[j], acc[i][j]);
        }
        #pragma unroll
        for (int i = 0; i < 4; ++i) {
            size_t row = (size_t)(b * KNN + kk) * TT + tb * 64 + 4 * tt + i;
            unsigned w0 = (unsigned)f2bf(acc[i][0]) | ((unsigned)f2bf(acc[i][1]) << 16);
            unsigned w1 = (unsigned)f2bf(acc[i][2]) | ((unsigned)f2bf(acc[i][3]) << 16);
            *(uint2*)&ub[row * CH + 4 * to] = make_uint2(w0, w1);
        }
        __syncthreads();
    }
}

// ---------------------------------------------------------------------------
// K2: barrier-free bf16-MFMA sim + top-4 prefilter + θ-collect + exact rescore
//     grid 512 = b(8, XCD swizzle) x ib(64); block 512 = 8 waves.
//     Wave (wr,wc): rows [wr*32,+32) (2 rt of 16) x cols [wc*1024,+1024).
//     jt = 32 iters x 32 cols (jj=2). Small per-jt set (~95 VGPR) +
//     waves_per_eu(4,4) -> 16 waves/CU, loads pipelined ahead of use.
// ---------------------------------------------------------------------------
__global__ __launch_bounds__(512) __attribute__((amdgpu_waves_per_eu(4, 4)))
void sim_topk_kernel(
        const unsigned short* __restrict__ qtb, const unsigned short* __restrict__ ktb,
        const float* __restrict__ qtf, const float* __restrict__ ktf,
        int* __restrict__ idxout) {
    __shared__ int   cnt[64];
    __shared__ int   bkt[64 * SLOTS];
    __shared__ float wbf[64 * SLOTS];

    const int b    = blockIdx.x & 7;
    const int ib   = blockIdx.x >> 3;      // 0..63
    const int tid  = threadIdx.x;
    const int lane = tid & 63;
    const int w    = tid >> 6;             // wave 0..7
    const int wr   = w >> 2;               // row half (32 rows)
    const int wc   = w & 3;                // col quarter (1024 cols)
    const int quad = lane >> 4;
    const int l15  = lane & 15;

    if (tid < 64) cnt[tid] = 0;
    __syncthreads();

    // k A-fragments in registers: rows ib*64 + wr*32 + rt*16 + l15
    const unsigned short* kb = ktb + ((size_t)b * TT + ib * 64 + wr * 32) * CH;
    s16x8 ka[2][2];
    #pragma unroll
    for (int rt = 0; rt < 2; ++rt)
        #pragma unroll
        for (int ks = 0; ks < 2; ++ks)
            ka[rt][ks] = *(const s16x8*)(kb + (size_t)(rt * 16 + l15) * CH + ks * 32 + quad * 8);

    const unsigned short* qbB = qtb + ((size_t)b * TT + wc * 1024) * CH;

    float s[2][4][4];
    #pragma unroll
    for (int rt = 0; rt < 2; ++rt)
        #pragma unroll
        for (int rg = 0; rg < 4; ++rg)
            #pragma unroll
            for (int k = 0; k < 4; ++k) s[rt][rg][k] = NEG_INF;

    // ------------------ PASS A: values-only top-4 (no barriers) ------------
    for (int jt = 0; jt < 32; ++jt) {
        s16x8 qf[2][2];
        #pragma unroll
        for (int jj = 0; jj < 2; ++jj)
            #pragma unroll
            for (int ks = 0; ks < 2; ++ks)
                qf[jj][ks] = *(const s16x8*)(qbB + (size_t)(jt * 32 + jj * 16 + l15) * CH + ks * 32 + quad * 8);

        f32x4 acc[2][2];
        #pragma unroll
        for (int rt = 0; rt < 2; ++rt)
            #pragma unroll
            for (int jj = 0; jj < 2; ++jj) acc[rt][jj] = (f32x4){0.f, 0.f, 0.f, 0.f};
        #pragma unroll
        for (int ks = 0; ks < 2; ++ks)
            #pragma unroll
            for (int rt = 0; rt < 2; ++rt)
                #pragma unroll
                for (int jj = 0; jj < 2; ++jj)
                    acc[rt][jj] = __builtin_amdgcn_mfma_f32_16x16x32_bf16(ka[rt][ks], qf[jj][ks], acc[rt][jj], 0, 0, 0);

        #pragma unroll
        for (int rt = 0; rt < 2; ++rt)
            #pragma unroll
            for (int jj = 0; jj < 2; ++jj) {
                insert4(acc[rt][jj][0], s[rt][0]);
                insert4(acc[rt][jj][1], s[rt][1]);
                insert4(acc[rt][jj][2], s[rt][2]);
                insert4(acc[rt][jj][3], s[rt][3]);
            }
    }

    // per-(row, col-quarter) θ
    float th[2][4];
    #pragma unroll
    for (int rt = 0; rt < 2; ++rt)
        #pragma unroll
        for (int rg = 0; rg < 4; ++rg)
            th[rt][rg] = popTheta4(s[rt][rg], lane);

    // ------------------ PASS B: recompute (bitwise-identical) + collect ----
    for (int jt = 0; jt < 32; ++jt) {
        s16x8 qf[2][2];
        #pragma unroll
        for (int jj = 0; jj < 2; ++jj)
            #pragma unroll
            for (int ks = 0; ks < 2; ++ks)
                qf[jj][ks] = *(const s16x8*)(qbB + (size_t)(jt * 32 + jj * 16 + l15) * CH + ks * 32 + quad * 8);

        f32x4 acc[2][2];
        #pragma unroll
        for (int rt = 0; rt < 2; ++rt)
            #pragma unroll
            for (int jj = 0; jj < 2; ++jj) acc[rt][jj] = (f32x4){0.f, 0.f, 0.f, 0.f};
        #pragma unroll
        for (int ks = 0; ks < 2; ++ks)
            #pragma unroll
            for (int rt = 0; rt < 2; ++rt)
                #pragma unroll
                for (int jj = 0; jj < 2; ++jj)
                    acc[rt][jj] = __builtin_amdgcn_mfma_f32_16x16x32_bf16(ka[rt][ks], qf[jj][ks], acc[rt][jj], 0, 0, 0);

        #pragma unroll
        for (int rt = 0; rt < 2; ++rt)
            #pragma unroll
            for (int jj = 0; jj < 2; ++jj) {
                const int j = wc * 1024 + jt * 32 + jj * 16 + l15;
                #pragma unroll
                for (int rg = 0; rg < 4; ++rg) {
                    if (acc[rt][jj][rg] >= th[rt][rg]) {
                        int rowl = wr * 32 + rt * 16 + quad * 4 + rg;
                        int sl = atomicAdd(&cnt[rowl], 1);
                        if (sl < SLOTS) bkt[rowl * SLOTS + sl] = j;
                    }
                }
            }
    }
    __syncthreads();

    // ------------------ exact fp32 rescore (8 threads/row) -----------------
    {
        int r = tid >> 3, sub = tid & 7;
        int n = min(cnt[r], SLOTS);
        const float* krow = ktf + ((size_t)b * TT + ib * 64 + r) * CH;
        for (int m = sub; m < n; m += 8) {
            int j = bkt[r * SLOTS + m];
            const float* qrow = qtf + ((size_t)b * TT + j) * CH;
            float wv = 0.f;
            #pragma unroll
            for (int c4 = 0; c4 < 16; ++c4) {
                float4 kv = *(const float4*)&krow[c4 * 4];
                float4 qv = *(const float4*)&qrow[c4 * 4];
                wv = fmaf(kv.x, qv.x, wv); wv = fmaf(kv.y, qv.y, wv);
                wv = fmaf(kv.z, qv.z, wv); wv = fmaf(kv.w, qv.w, wv);
            }
            wbf[r * SLOTS + m] = wv;
        }
    }
    __syncthreads();

    if (tid < 64) {
        int n = min(cnt[tid], SLOTS);
        float s9[9]; int si9[9];
        #pragma unroll
        for (int k = 0; k < 9; ++k) { s9[k] = NEG_INF; si9[k] = 0x7fffffff; }
        #pragma unroll 1
        for (int m = 0; m < n; ++m) insert9x(wbf[tid * SLOTS + m], bkt[tid * SLOTS + m], s9, si9);
        int* orow = idxout + ((size_t)b * TT + ib * 64 + tid) * KNN;
        #pragma unroll
        for (int m = 0; m < 9; ++m) orow[m] = si9[8 - m];
    }
}

// ---------------------------------------------------------------------------
// K3: out[b][o][t] = conv_b[o] + sum_kk u_bf16[b][kk][idx[t][kk]][o]
// ---------------------------------------------------------------------------
__global__ __launch_bounds__(256) void gather_conv_kernel(
        const unsigned short* __restrict__ ub, const int* __restrict__ idxin,
        const float* __restrict__ conv_b, float* __restrict__ out) {
    __shared__ int   sidx[64 * KNN];
    __shared__ float cb[CH];
    const int b   = blockIdx.x & 7;
    const int tb  = blockIdx.x >> 3;
    const int tid = threadIdx.x;

    if (tid < CH) cb[tid] = conv_b[tid];
    const int* ig = idxin + ((size_t)b * TT + tb * 64) * KNN;
    for (int l = tid; l < 64 * KNN; l += 256) sidx[l] = ig[l];
    __syncthreads();

    const int tl = tid & 63;
    const int og = tid >> 6;
    const int o0 = og * 16;

    float acc[16];
    #pragma unroll
    for (int q = 0; q < 16; ++q) acc[q] = cb[o0 + q];

    #pragma unroll
    for (int kk = 0; kk < KNN; ++kk) {
        int j = sidx[tl * KNN + kk];
        const unsigned short* up = ub + (((size_t)(b * KNN + kk)) * TT + j) * CH + o0;
        #pragma unroll
        for (int q8 = 0; q8 < 2; ++q8) {
            uint4 raw = *(const uint4*)&up[q8 * 8];
            unsigned rw[4] = {raw.x, raw.y, raw.z, raw.w};
            #pragma unroll
            for (int p = 0; p < 4; ++p) {
                acc[q8 * 8 + 2 * p]     += __uint_as_float(rw[p] << 16);
                acc[q8 * 8 + 2 * p + 1] += __uint_as_float(rw[p] & 0xFFFF0000u);
            }
        }
    }
    const int t = tb * 64 + tl;
    #pragma unroll
    for (int q = 0; q < 16; ++q)
        out[((size_t)b * CH + o0 + q) * TT + t] = acc[q];
}

// ---------------------------------------------------------------------------
extern "C" void kernel_launch(void* const* d_in, const int* in_sizes, int n_in,
                              void* d_out, int out_size, void* d_ws, size_t ws_size,
                              hipStream_t stream) {
    const float* x   = (const float*)d_in[0];
    const float* Wq  = (const float*)d_in[1];
    const float* Wk  = (const float*)d_in[2];
    const float* Wv  = (const float*)d_in[3];
    const float* cw  = (const float*)d_in[4];
    const float* cbp = (const float*)d_in[5];

    float* ws = (float*)d_ws;
    unsigned short* ub  = (unsigned short*)(ws + OFF_UB);
    float* qtf          = ws + OFF_QTF;
    float* ktf          = ws + OFF_KTF;
    unsigned short* qtb = (unsigned short*)(ws + OFF_QTB);
    unsigned short* ktb = (unsigned short*)(ws + OFF_KTB);
    int*   idx          = (int*)(ws + OFF_IDX);
    float* cwp          = ws + OFF_CWP;
    float* out          = (float*)d_out;

    repack_cw_kernel<<<(KNN * CH * CH + 255) / 256, 256, 0, stream>>>(cw, cwp);
    qkvu_kernel<<<BB * 64, 256, 0, stream>>>(x, Wq, Wk, Wv, cwp, qtf, ktf, qtb, ktb, ub);
    sim_topk_kernel<<<BB * 64, 512, 0, stream>>>(qtb, ktb, qtf, ktf, idx);
    gather_conv_kernel<<<BB * 64, 256, 0, stream>>>(ub, idx, cbp, out);
}

// Round 11
// 341.543 us; speedup vs baseline: 1.0829x; 1.0829x over previous
//
#include <hip/hip_runtime.h>
#include <hip/hip_bf16.h>
#include <cstdint>

// Problem constants
#define BB  8
#define CH  64
#define TT  4096
#define KNN 9
#define NEG_INF (-3.402823466e38f)
#define NPOP 24           // candidates popped (and rescored) per row

typedef short  s16x8 __attribute__((ext_vector_type(8)));   // 8 bf16 MFMA frag
typedef float  f32x4 __attribute__((ext_vector_type(4)));   // MFMA acc

// Workspace layout (float units) — end 16,060,416 floats = 64.2 MB
constexpr size_t OFF_UB  = 0;                                  // u bf16 [B][9][T][C] ushort
constexpr size_t OFF_QTF = (size_t)BB*KNN*TT*CH/2;             //  9,437,184 qhatT f32 [B][T][C]
constexpr size_t OFF_KTF = OFF_QTF + (size_t)BB*TT*CH;         // 11,534,336 khatT f32
constexpr size_t OFF_QTB = OFF_KTF + (size_t)BB*TT*CH;         // 13,631,488 qhatT bf16 ushort
constexpr size_t OFF_KTB = OFF_QTB + (size_t)BB*TT*CH/2;       // 14,680,064 khatT bf16
constexpr size_t OFF_IDX = OFF_KTB + (size_t)BB*TT*CH/2;       // 15,728,640 idx [B][T][9]
constexpr size_t OFF_CWP = OFF_IDX + (size_t)BB*TT*KNN;        // 16,023,552 cwp [9][64][64]

__device__ __forceinline__ unsigned short f2bf(float f) {
    unsigned u = __float_as_uint(f);
    return (unsigned short)((u + 0x7FFFu + ((u >> 16) & 1u)) >> 16);
}

// packed key: v in [-1,1] -> v+1.5 in [0.5,2.5] positive (bit-ordered).
// high 20 bits = quantized value, low 12 = (4095 - j): bigger key = bigger
// value, tie -> smaller j. Keys are globally unique per row (j distinct).
__device__ __forceinline__ int enc(float v, int ji) {
    return (int)((__float_as_uint(v + 1.5f) & 0xFFFFF000u) | (unsigned)ji);
}

// unconditional sorted top-10 insert (ascending; s[9]=max). min(b,max(a,w))
// == med3(a,b,w) for a<=b -> v_med3_i32 candidates. Reference params: SROA.
__device__ __forceinline__ void ins10(int w, int (&s)[10]) {
    #pragma unroll
    for (int k = 0; k < 9; ++k) s[k] = min(s[k + 1], max(s[k], w));
    s[9] = max(s[9], w);
}

// pop NPOP largest keys from the 16 lists across a quad (lanes sharing
// lane&48). Keys unique -> owner test is just h==m, no ballot. Lane 0 of the
// quad writes each popped key (m is quad-uniform after the reduction).
__device__ __forceinline__ void pop24(int (&s)[10], int lane, int* dstrow) {
    #pragma unroll 1
    for (int p = 0; p < NPOP; ++p) {
        int h = s[9];
        int m = h;
        m = max(m, __shfl_xor(m, 1));
        m = max(m, __shfl_xor(m, 2));
        m = max(m, __shfl_xor(m, 4));
        m = max(m, __shfl_xor(m, 8));
        if (h == m) {
            #pragma unroll
            for (int k = 9; k > 0; --k) s[k] = s[k - 1];
            s[0] = 0;
        }
        if ((lane & 15) == 0) dstrow[p] = m;
    }
}

// exact sorted-9 insert, value desc w/ index-asc tiebreak (final sort only)
__device__ __forceinline__ void insert9x(float w, int wi, float (&s)[9], int (&si)[9]) {
    bool c[9];
    #pragma unroll
    for (int k = 0; k < 9; ++k) c[k] = (w > s[k]) || (w == s[k] && wi < si[k]);
    #pragma unroll
    for (int k = 0; k < 8; ++k) si[k] = c[k + 1] ? si[k + 1] : (c[k] ? wi : si[k]);
    si[8] = c[8] ? wi : si[8];
    #pragma unroll
    for (int k = 0; k < 8; ++k) s[k] = c[k + 1] ? s[k + 1] : (c[k] ? w : s[k]);
    s[8] = c[8] ? w : s[8];
}

// ---------------------------------------------------------------------------
// K0: repack conv_w[o][cc*9+kk] -> cwp[kk][cc][o]
// ---------------------------------------------------------------------------
__global__ void repack_cw_kernel(const float* __restrict__ cw, float* __restrict__ cwp) {
    int e = blockIdx.x * blockDim.x + threadIdx.x;
    if (e >= KNN * CH * CH) return;
    int o  = e & 63;
    int cc = (e >> 6) & 63;
    int kk = e >> 12;
    cwp[e] = cw[o * (CH * KNN) + cc * KNN + kk];
}

// ---------------------------------------------------------------------------
// K1: QKV + L2 normalize + u-projection (u bf16) + q/k T-layout fp32 & bf16
// ---------------------------------------------------------------------------
__global__ __launch_bounds__(256) void qkvu_kernel(
        const float* __restrict__ x,
        const float* __restrict__ Wq, const float* __restrict__ Wk, const float* __restrict__ Wv,
        const float* __restrict__ cwp,
        float* __restrict__ qtf, float* __restrict__ ktf,
        unsigned short* __restrict__ qtb, unsigned short* __restrict__ ktb,
        unsigned short* __restrict__ ub) {
    __shared__ __align__(16) float xs[CH * 64];
    __shared__ __align__(16) float vs[CH * 64];
    __shared__ __align__(16) float wl[CH * 64];
    __shared__ float pq[4 * 64], pk[4 * 64];

    const int b   = blockIdx.x >> 6;
    const int tb  = blockIdx.x & 63;
    const int tid = threadIdx.x;

    const float* xb = x + ((size_t)b * CH) * TT + tb * 64;
    #pragma unroll
    for (int m = 0; m < 16; ++m) {
        int l = tid + 256 * m;
        xs[l] = xb[(size_t)(l >> 6) * TT + (l & 63)];
    }
    __syncthreads();

    const int t = tid & 63;
    const int g = __builtin_amdgcn_readfirstlane(tid >> 6);
    const int d0 = g * 16;

    float qa[16], ka[16], va[16];
    #pragma unroll
    for (int dd = 0; dd < 16; ++dd) { qa[dd] = 0.f; ka[dd] = 0.f; va[dd] = 0.f; }

    #pragma unroll 4
    for (int c = 0; c < CH; ++c) {
        float xv = xs[c * 64 + t];
        #pragma unroll
        for (int dd = 0; dd < 16; ++dd) {
            qa[dd] = fmaf(Wq[(d0 + dd) * CH + c], xv, qa[dd]);
            ka[dd] = fmaf(Wk[(d0 + dd) * CH + c], xv, ka[dd]);
            va[dd] = fmaf(Wv[(d0 + dd) * CH + c], xv, va[dd]);
        }
    }

    float sq = 0.f, sk = 0.f;
    #pragma unroll
    for (int dd = 0; dd < 16; ++dd) { sq = fmaf(qa[dd], qa[dd], sq); sk = fmaf(ka[dd], ka[dd], sk); }
    pq[g * 64 + t] = sq;
    pk[g * 64 + t] = sk;
    __syncthreads();

    const float nq = sqrtf(pq[t] + pq[64 + t] + pq[128 + t] + pq[192 + t]);
    const float nk = sqrtf(pk[t] + pk[64 + t] + pk[128 + t] + pk[192 + t]);
    const float isq = 1.0f / fmaxf(nq, 1e-12f);
    const float isk = 1.0f / fmaxf(nk, 1e-12f);

    const size_t tg = (size_t)tb * 64 + t;
    float qn[16], kn[16];
    #pragma unroll
    for (int dd = 0; dd < 16; ++dd) {
        qn[dd] = qa[dd] * isq;
        kn[dd] = ka[dd] * isk;
        vs[(d0 + dd) * 64 + t] = va[dd];
    }
    float* qf = qtf + ((size_t)b * TT + tg) * CH + d0;
    float* kf = ktf + ((size_t)b * TT + tg) * CH + d0;
    #pragma unroll
    for (int p = 0; p < 4; ++p) {
        *(float4*)&qf[p * 4] = make_float4(qn[p*4], qn[p*4+1], qn[p*4+2], qn[p*4+3]);
        *(float4*)&kf[p * 4] = make_float4(kn[p*4], kn[p*4+1], kn[p*4+2], kn[p*4+3]);
    }
    unsigned* qh = (unsigned*)(qtb + ((size_t)b * TT + tg) * CH + d0);
    unsigned* kh = (unsigned*)(ktb + ((size_t)b * TT + tg) * CH + d0);
    #pragma unroll
    for (int p = 0; p < 8; ++p) {
        qh[p] = (unsigned)f2bf(qn[2*p]) | ((unsigned)f2bf(qn[2*p+1]) << 16);
        kh[p] = (unsigned)f2bf(kn[2*p]) | ((unsigned)f2bf(kn[2*p+1]) << 16);
    }
    __syncthreads();

    const int to = tid & 15;
    const int tt = tid >> 4;
    for (int kk = 0; kk < KNN; ++kk) {
        #pragma unroll
        for (int m = 0; m < 16; ++m) {
            int l = tid + 256 * m;
            wl[l] = cwp[kk * (CH * CH) + l];
        }
        __syncthreads();
        float acc[4][4];
        #pragma unroll
        for (int i = 0; i < 4; ++i)
            #pragma unroll
            for (int j = 0; j < 4; ++j) acc[i][j] = 0.f;

        #pragma unroll 8
        for (int cc = 0; cc < CH; ++cc) {
            float4 wv = *(const float4*)&wl[cc * 64 + 4 * to];
            float4 vv = *(const float4*)&vs[cc * 64 + 4 * tt];
            const float wj[4] = {wv.x, wv.y, wv.z, wv.w};
            const float vi[4] = {vv.x, vv.y, vv.z, vv.w};
            #pragma unroll
            for (int i = 0; i < 4; ++i)
                #pragma unroll
                for (int j = 0; j < 4; ++j) acc[i][j] = fmaf(vi[i], wj[j], acc[i][j]);
        }
        #pragma unroll
        for (int i = 0; i < 4; ++i) {
            size_t row = (size_t)(b * KNN + kk) * TT + tb * 64 + 4 * tt + i;
            unsigned w0 = (unsigned)f2bf(acc[i][0]) | ((unsigned)f2bf(acc[i][1]) << 16);
            unsigned w1 = (unsigned)f2bf(acc[i][2]) | ((unsigned)f2bf(acc[i][3]) << 16);
            *(uint2*)&ub[row * CH + 4 * to] = make_uint2(w0, w1);
        }
        __syncthreads();
    }
}

// ---------------------------------------------------------------------------
// helpers for K2's register-double-buffered q loads
// ---------------------------------------------------------------------------
__device__ __forceinline__ void loadQ(s16x8 (&qf)[4][2], const unsigned short* __restrict__ qb,
                                      int jt, int l15, int quad) {
    #pragma unroll
    for (int jj = 0; jj < 4; ++jj)
        #pragma unroll
        for (int ks = 0; ks < 2; ++ks)
            qf[jj][ks] = *(const s16x8*)(qb + (size_t)(jt * 64 + jj * 16 + l15) * CH + ks * 32 + quad * 8);
}

__device__ __forceinline__ void computeTile(const s16x8 (&qf)[4][2], const s16x8 (&ka)[2],
        int jt, int l15,
        int (&L0)[10], int (&L1)[10], int (&L2)[10], int (&L3)[10]) {
    f32x4 acc[4];
    #pragma unroll
    for (int jj = 0; jj < 4; ++jj) acc[jj] = (f32x4){0.f, 0.f, 0.f, 0.f};
    #pragma unroll
    for (int ks = 0; ks < 2; ++ks)
        #pragma unroll
        for (int jj = 0; jj < 4; ++jj)
            acc[jj] = __builtin_amdgcn_mfma_f32_16x16x32_bf16(ka[ks], qf[jj][ks], acc[jj], 0, 0, 0);

    const int jinv = 4095 - jt * 64 - l15;
    #pragma unroll
    for (int jj = 0; jj < 4; ++jj) {
        const int ji = jinv - jj * 16;
        ins10(enc(acc[jj][0], ji), L0);
        ins10(enc(acc[jj][1], ji), L1);
        ins10(enc(acc[jj][2], ji), L2);
        ins10(enc(acc[jj][3], ji), L3);
    }
}

// ---------------------------------------------------------------------------
// K2: single-pass bf16-MFMA sim + packed-key top-10/lane + pop-24 + rescore
//     grid 512 = b(8, XCD swizzle) x ib(64); block 256 = 4 waves.
//     Wave wv owns rows [ib*64 + wv*16, +16), scans all 4096 cols.
//     jt = 64 iters x 64 cols; q B-frags register-double-buffered (prefetch
//     next jt before computing current -> one vmcnt wait per jt, ~full-iter
//     lead time). No pass B, no atomics, no barriers in the main loop.
// ---------------------------------------------------------------------------
__global__ __launch_bounds__(256) __attribute__((amdgpu_waves_per_eu(2, 2)))
void sim_topk_kernel(
        const unsigned short* __restrict__ qtb, const unsigned short* __restrict__ ktb,
        const float* __restrict__ qtf, const float* __restrict__ ktf,
        int* __restrict__ idxout) {
    __shared__ int   keys[64 * NPOP];
    __shared__ float wbf[64 * NPOP];

    const int b    = blockIdx.x & 7;
    const int ib   = blockIdx.x >> 3;      // 0..63
    const int tid  = threadIdx.x;
    const int lane = tid & 63;
    const int wv   = tid >> 6;             // wave 0..3
    const int quad = lane >> 4;
    const int l15  = lane & 15;
    const int i0   = wv * 16;              // wave's block-local row base

    // k A-fragments (rows ib*64 + i0 + l15), registers, loaded once
    const unsigned short* kb = ktb + ((size_t)b * TT + ib * 64 + i0) * CH;
    s16x8 ka[2];
    #pragma unroll
    for (int ks = 0; ks < 2; ++ks)
        ka[ks] = *(const s16x8*)(kb + (size_t)l15 * CH + ks * 32 + quad * 8);

    const unsigned short* qb = qtb + (size_t)b * TT * CH;

    int L0[10], L1[10], L2[10], L3[10];
    #pragma unroll
    for (int k = 0; k < 10; ++k) { L0[k] = 0; L1[k] = 0; L2[k] = 0; L3[k] = 0; }

    s16x8 qfA[4][2], qfB[4][2];
    loadQ(qfA, qb, 0, l15, quad);

    #pragma unroll 1
    for (int jt2 = 0; jt2 < 32; ++jt2) {
        const int jtA = 2 * jt2, jtB = 2 * jt2 + 1;
        loadQ(qfB, qb, jtB, l15, quad);                 // prefetch B
        computeTile(qfA, ka, jtA, l15, L0, L1, L2, L3); // consume A
        if (jtA + 2 < 64) loadQ(qfA, qb, jtA + 2, l15, quad);  // prefetch next A
        computeTile(qfB, ka, jtB, l15, L0, L1, L2, L3); // consume B
    }

    // pop the 24 best keys per row (quad-parallel; rows i0+quad*4+rg)
    pop24(L0, lane, &keys[(i0 + quad * 4 + 0) * NPOP]);
    pop24(L1, lane, &keys[(i0 + quad * 4 + 1) * NPOP]);
    pop24(L2, lane, &keys[(i0 + quad * 4 + 2) * NPOP]);
    pop24(L3, lane, &keys[(i0 + quad * 4 + 3) * NPOP]);
    __syncthreads();

    // exact fp32 rescore: 4 threads/row x 6 candidates
    {
        int r = tid >> 2, sub = tid & 3;
        const float* krow = ktf + ((size_t)b * TT + ib * 64 + r) * CH;
        #pragma unroll
        for (int mm = 0; mm < 6; ++mm) {
            int m = sub + 4 * mm;
            int j = 4095 - (keys[r * NPOP + m] & 0xFFF);
            const float* qrow = qtf + ((size_t)b * TT + j) * CH;
            float wval = 0.f;
            #pragma unroll
            for (int c4 = 0; c4 < 16; ++c4) {
                float4 kv = *(const float4*)&krow[c4 * 4];
                float4 qv = *(const float4*)&qrow[c4 * 4];
                wval = fmaf(kv.x, qv.x, wval); wval = fmaf(kv.y, qv.y, wval);
                wval = fmaf(kv.z, qv.z, wval); wval = fmaf(kv.w, qv.w, wval);
            }
            wbf[r * NPOP + m] = wval;
        }
    }
    __syncthreads();

    if (tid < 64) {
        float s9[9]; int si9[9];
        #pragma unroll
        for (int k = 0; k < 9; ++k) { s9[k] = NEG_INF; si9[k] = 0x7fffffff; }
        #pragma unroll 1
        for (int m = 0; m < NPOP; ++m) {
            int j = 4095 - (keys[tid * NPOP + m] & 0xFFF);
            insert9x(wbf[tid * NPOP + m], j, s9, si9);
        }
        int* orow = idxout + ((size_t)b * TT + ib * 64 + tid) * KNN;
        #pragma unroll
        for (int m = 0; m < 9; ++m) orow[m] = si9[8 - m];
    }
}

// ---------------------------------------------------------------------------
// K3: out[b][o][t] = conv_b[o] + sum_kk u_bf16[b][kk][idx[t][kk]][o]
// ---------------------------------------------------------------------------
__global__ __launch_bounds__(256) void gather_conv_kernel(
        const unsigned short* __restrict__ ub, const int* __restrict__ idxin,
        const float* __restrict__ conv_b, float* __restrict__ out) {
    __shared__ int   sidx[64 * KNN];
    __shared__ float cb[CH];
    const int b   = blockIdx.x & 7;
    const int tb  = blockIdx.x >> 3;
    const int tid = threadIdx.x;

    if (tid < CH) cb[tid] = conv_b[tid];
    const int* ig = idxin + ((size_t)b * TT + tb * 64) * KNN;
    for (int l = tid; l < 64 * KNN; l += 256) sidx[l] = ig[l];
    __syncthreads();

    const int tl = tid & 63;
    const int og = tid >> 6;
    const int o0 = og * 16;

    float acc[16];
    #pragma unroll
    for (int q = 0; q < 16; ++q) acc[q] = cb[o0 + q];

    #pragma unroll
    for (int kk = 0; kk < KNN; ++kk) {
        int j = sidx[tl * KNN + kk];
        const unsigned short* up = ub + (((size_t)(b * KNN + kk)) * TT + j) * CH + o0;
        #pragma unroll
        for (int q8 = 0; q8 < 2; ++q8) {
            uint4 raw = *(const uint4*)&up[q8 * 8];
            unsigned rw[4] = {raw.x, raw.y, raw.z, raw.w};
            #pragma unroll
            for (int p = 0; p < 4; ++p) {
                acc[q8 * 8 + 2 * p]     += __uint_as_float(rw[p] << 16);
                acc[q8 * 8 + 2 * p + 1] += __uint_as_float(rw[p] & 0xFFFF0000u);
            }
        }
    }
    const int t = tb * 64 + tl;
    #pragma unroll
    for (int q = 0; q < 16; ++q)
        out[((size_t)b * CH + o0 + q) * TT + t] = acc[q];
}

// ---------------------------------------------------------------------------
extern "C" void kernel_launch(void* const* d_in, const int* in_sizes, int n_in,
                              void* d_out, int out_size, void* d_ws, size_t ws_size,
                              hipStream_t stream) {
    const float* x   = (const float*)d_in[0];
    const float* Wq  = (const float*)d_in[1];
    const float* Wk  = (const float*)d_in[2];
    const float* Wv  = (const float*)d_in[3];
    const float* cw  = (const float*)d_in[4];
    const float* cbp = (const float*)d_in[5];

    float* ws = (float*)d_ws;
    unsigned short* ub  = (unsigned short*)(ws + OFF_UB);
    float* qtf          = ws + OFF_QTF;
    float* ktf          = ws + OFF_KTF;
    unsigned short* qtb = (unsigned short*)(ws + OFF_QTB);
    unsigned short* ktb = (unsigned short*)(ws + OFF_KTB);
    int*   idx          = (int*)(ws + OFF_IDX);
    float* cwp          = ws + OFF_CWP;
    float* out          = (float*)d_out;

    repack_cw_kernel<<<(KNN * CH * CH + 255) / 256, 256, 0, stream>>>(cw, cwp);
    qkvu_kernel<<<BB * 64, 256, 0, stream>>>(x, Wq, Wk, Wv, cwp, qtf, ktf, qtb, ktb, ub);
    sim_topk_kernel<<<BB * 64, 256, 0, stream>>>(qtb, ktb, qtf, ktf, idx);
    gather_conv_kernel<<<BB * 64, 256, 0, stream>>>(ub, idx, cbp, out);
}